// Round 13
// baseline (77.089 us; speedup 1.0000x reference)
//
#include <hip/hip_runtime.h>
#include <stdint.h>

// Fused BSQ: recon = sign(x @ Wp + bp) @ Wr + br   (L2-normalize is sign-invariant)
// x: [65536][512] f32, Wp: [512][16], bp: [16], Wr: [16][512], br: [512]
//
// Round-13: persistent multi-tile blocks. 1024 blocks x 64 rows = whole grid
// co-resident (4 blocks/CU: LDS 23.5KB, VGPR<=128). Weights loaded ONCE per
// block; ONE WAITV(0) per block. Rows stream through 8-row groups:
//   chunks (2-row dots + stage-ahead into 4-slot DMA ring) -> lgkm-only BAR
//   -> recon of the PREVIOUS group. zp is 3-way banked so the single BAR per
//   group orders both RAW (dots->recon) and WAR (recon->dots two groups later;
//   the intervening BAR covers it since BAR's lgkmcnt(0) retires reads).
// vmcnt: per group per wave = 4 stages + 8 recon stores -> steady WAITV(11);
// group 1 WAITV(3) (no stores yet); last group 11-c countdown (no stages).
// pk-FMA dot/recon, zp[bank][rg][d][wave] conflict-free, float2 stores.
// Rare (~2%) exact-f64 fixup post-loop (uniform, matched barriers).
// Reference signs are f64-exact: rounds 1-12 absmax 0.0.

#define ROWS   65536
#define RPB    64               // rows per block
#define BLOCKS (ROWS / RPB)     // 1024
#define TAU    1e-3f

#define BAR()    asm volatile("s_waitcnt lgkmcnt(0)\n\ts_barrier" ::: "memory")
#define WAITV(N) asm volatile("s_waitcnt vmcnt(" #N ")" ::: "memory")
#define WAITL()  asm volatile("s_waitcnt lgkmcnt(0)" ::: "memory")
#define CFENCE() asm volatile("" ::: "memory")

typedef const __attribute__((address_space(1))) void* gas1_t;
typedef __attribute__((address_space(3))) void*       las3_t;
typedef float v2f __attribute__((ext_vector_type(2)));

__global__ __launch_bounds__(256, 2)
void bsq_fused(const float* __restrict__ x,
               const float* __restrict__ Wp,
               const float* __restrict__ bp,
               const float* __restrict__ Wr,
               const float* __restrict__ br,
               float* __restrict__ out)
{
    const int tid = threadIdx.x;
    const int w   = tid >> 6;      // wave 0..3: c-quarter
    const int l   = tid & 63;
    const int cg  = l >> 4;        // 0..3
    const int dg  = l & 15;        // 0..15: this lane's d

    __shared__ __align__(16) float  xl[4 * 1024];       // 16 KB ring (4 slots x 2 rows)
    __shared__ __align__(16) float  zp[3][8][16][4];    // 6 KB: 3 banks x 8 rows
    __shared__ __align__(16) double zb64[4][16];        // fixup exchange

    // ---- ALL weights, once per block (drained by the single WAITV(0)) ----
    v2f wpA[8], wpB[8];
#pragma unroll
    for (int j = 0; j < 8; ++j) {
        const float* wj = Wp + (w * 128 + j * 16 + cg * 4) * 16 + dg;
        wpA[j] = (v2f){ wj[0],  wj[16] };
        wpB[j] = (v2f){ wj[32], wj[48] };
    }
    const float bpf = bp[dg];

    v2f wrv[16];
    const float2* Wr2 = (const float2*)Wr;
#pragma unroll
    for (int d = 0; d < 16; ++d) {
        const float2 t = Wr2[d * 256 + tid];
        wrv[d] = (v2f){ t.x, t.y };
    }
    const float2 brt = ((const float2*)br)[tid];
    const v2f br2v = (v2f){ brt.x, brt.y };

    const int row0 = blockIdx.x * RPB;
    const float* xsrc = x + (size_t)row0 * 512 + (size_t)(l >> 5) * 512
                          + w * 128 + (l & 31) * 4;

    auto stage = [&](int s) {      // rows 2s,2s+1: wave's 1 KB region, 1 DMA
        __builtin_amdgcn_global_load_lds(
            (gas1_t)(xsrc + (size_t)(2 * s) * 512),
            (las3_t)(&xl[(s & 3) * 1024 + w * 256]), 16, 0, 0);
    };

    auto dot_part = [&](int s, int p, v2f& accA, v2f& accB) {
        const float* bx = &xl[(s & 3) * 1024 + w * 256 + p * 128 + cg * 4];
        float4 xr[8];
#pragma unroll
        for (int j = 0; j < 8; ++j) xr[j] = *(const float4*)(bx + j * 16);
        accA = (v2f){0.f, 0.f};  accB = (v2f){0.f, 0.f};
#pragma unroll
        for (int j = 0; j < 8; ++j) {
            accA += (v2f){ xr[j].x, xr[j].y } * wpA[j];   // v_pk_fma_f32
            accB += (v2f){ xr[j].z, xr[j].w } * wpB[j];
        }
    };
    auto fin_part = [&](int bank, int rg, v2f accA, v2f accB) {
        float a = (accA.x + accA.y) + (accB.x + accB.y);
        a += __shfl_xor(a, 16, 64);
        a += __shfl_xor(a, 32, 64);
        if (l < 16) zp[bank][rg][l][w] = a;   // 2-way bank alias = free
    };

    // chunk: dots for rows 2s,2s+1 -> zp[bank][rg..rg+1]; optional stage-ahead
    auto chunk = [&](int s, int bank, int rg, bool do_stage) {
        v2f aA0, aB0, aA1, aB1;
        dot_part(s, 0, aA0, aB0);
        dot_part(s, 1, aA1, aB1);
        CFENCE();
        WAITL();                       // slot's ds_reads retired -> reusable
        if (do_stage) stage(s + 4);
        CFENCE();
        fin_part(bank, rg,     aA0, aB0);
        fin_part(bank, rg + 1, aA1, aB1);
    };

    unsigned long long amb = 0ull;     // block-uniform ambiguity mask (64 rows)
    auto recon_row = [&](int bank, int rg, int r) {
        const float4 q = *(const float4*)&zp[bank][rg][dg][0];
        const float  z = (q.x + q.y) + (q.z + q.w) + bpf;
        if (__ballot(fabsf(z) < TAU)) amb |= (1ull << r);
        const int m = (int)(__ballot(z >= 0.0f) & 0xFFFFull);
        v2f o = br2v;
#pragma unroll
        for (int d = 0; d < 16; ++d) {
            const float s = ((m >> d) & 1) ? 1.0f : -1.0f;
            o += (v2f){ s, s } * wrv[d];                  // v_pk_fma_f32
        }
        ((float2*)out)[(size_t)(row0 + r) * 256 + tid] = make_float2(o.x, o.y);
    };

    // ======================= pipeline over 8 groups =======================
#pragma unroll
    for (int s = 0; s < 4; ++s) stage(s);
    WAITV(0);   // weights + slots 0..3 resident; vm-counting exact from here

    // group 0: dots rows 0..7 (pre-drained), stage rows 8..15
#pragma unroll
    for (int c = 0; c < 4; ++c) chunk(c, 0, 2 * c, true);
    BAR();

    // group 1: WAITV(3) (3 newer stages in flight; no stores yet)
#pragma unroll
    for (int c = 0; c < 4; ++c) { WAITV(3); chunk(4 + c, 1, 2 * c, true); }
    BAR();
#pragma unroll
    for (int rg = 0; rg < 8; ++rg) recon_row(0, rg, rg);

    // groups 2..6: steady state WAITV(11) = 3 stages + 8 stores + c stages
#pragma unroll 1
    for (int g = 2; g < 7; ++g) {
        const int bank = g % 3, pbank = (g - 1) % 3;
#pragma unroll
        for (int c = 0; c < 4; ++c) {
            WAITV(11);
            chunk(4 * g + c, bank, 2 * c, true);
        }
        BAR();
#pragma unroll
        for (int rg = 0; rg < 8; ++rg) recon_row(pbank, rg, 8 * (g - 1) + rg);
    }

    // group 7: no staging; in-flight shrinks 11-c
    WAITV(11); chunk(28, 1, 0, false);
    WAITV(10); chunk(29, 1, 2, false);
    WAITV(9);  chunk(30, 1, 4, false);
    WAITV(8);  chunk(31, 1, 6, false);
    BAR();
#pragma unroll
    for (int rg = 0; rg < 8; ++rg) recon_row(0, rg, 48 + rg);   // group 6 (bank 0)
#pragma unroll
    for (int rg = 0; rg < 8; ++rg) recon_row(1, rg, 56 + rg);   // group 7 (bank 1)

    // ===== Fixup: rare exact-f64 redo; uniform loop, matched barriers =====
    const double bpd = (double)bpf;
#pragma unroll 1
    while (amb) {
        const int rr = __ffsll(amb) - 1;
        amb &= amb - 1;
        const int row = row0 + rr;

        const float* xp = x + (size_t)row * 512 + w * 128 + cg * 4;
        double ad = 0.0;
#pragma unroll
        for (int j = 0; j < 8; ++j) {
            const float4 xf = *(const float4*)(xp + j * 16);
#pragma unroll
            for (int e = 0; e < 4; ++e) {
                const float wpe = Wp[(w * 128 + j * 16 + cg * 4 + e) * 16 + dg];
                const float xe  = e == 0 ? xf.x : e == 1 ? xf.y
                               : e == 2 ? xf.z : xf.w;
                ad = fma((double)xe, (double)wpe, ad);
            }
        }
        ad += __shfl_xor(ad, 16, 64);
        ad += __shfl_xor(ad, 32, 64);
        if (l < 16) zb64[w][l] = ad;
        BAR();
        const double zd = (zb64[0][dg] + zb64[1][dg])
                        + (zb64[2][dg] + zb64[3][dg]) + bpd;
        const int m = (int)(__ballot(zd >= 0.0) & 0xFFFFull);
        BAR();   // zb64 reads retired before next fixup row's rewrite

        v2f o = br2v;
#pragma unroll
        for (int d = 0; d < 16; ++d) {
            const float s = ((m >> d) & 1) ? 1.0f : -1.0f;
            o += (v2f){ s, s } * wrv[d];
        }
        ((float2*)out)[(size_t)row * 256 + tid] = make_float2(o.x, o.y);
    }
}

extern "C" void kernel_launch(void* const* d_in, const int* in_sizes, int n_in,
                              void* d_out, int out_size, void* d_ws, size_t ws_size,
                              hipStream_t stream) {
    const float* x  = (const float*)d_in[0];
    const float* Wp = (const float*)d_in[1];
    const float* bp = (const float*)d_in[2];
    const float* Wr = (const float*)d_in[3];
    const float* br = (const float*)d_in[4];
    float* out = (float*)d_out;

    bsq_fused<<<BLOCKS, 256, 0, stream>>>(x, Wp, bp, Wr, br, out);
}

// Round 14
// 67.506 us; speedup vs baseline: 1.1420x; 1.1420x over previous
//
#include <hip/hip_runtime.h>
#include <stdint.h>

// Fused BSQ: recon = sign(x @ Wp + bp) @ Wr + br   (L2-normalize is sign-invariant)
// x: [65536][512] f32, Wp: [512][16], bp: [16], Wr: [16][512], br: [512]
//
// Round-14 = round-12 skeleton (best: 63.8us) with the LDS-broadcast
// amplification removed from the dot:
//  - OLD: lane covered 16d x 32c -> read 128 B/row from LDS, 16-way broadcast,
//    8 KB delivered/wave/row => ~41 us of LDS data-return time (the hidden
//    floor; m134: ~12cyc/b128 regardless of broadcast).
//  - NEW: lane (dq=l>>4, cl=l&15) covers 4d x 8c (c = w*128 + cl*4 + {0..3}
//    and +64): 2 distinct-address b128 = 2 KB/wave/row delivered (4x less).
//  - Reduction over cl: reduce-scatter. xor1/xor2 via DPP quad_perm (0xB1 /
//    0x4E - pure VALU, no LDS port) with give/keep selects; xor4/xor8 via
//    ds_swizzle. Lane ends with d(l) = (l>>4)*4 + (l&3); lanes l&12==0 write
//    zp[r][d][w] (16 banks, 2-way alias).
//  - Ballot bit positions permuted (d at lane (d>>2)*16 + (d&3)) -> mask
//    rebuilt with 4 scalar shift/ors. Recon weights stay in natural d order.
//  - Ring/vmcnt/two-half/interleave/fixup IDENTICAL to r12 (proven).
//    Reference signs are f64-exact: rounds 1-13 absmax 0.0.

#define ROWS   65536
#define TILE   16
#define BLOCKS (ROWS / TILE)   // 4096
#define TAU    1e-3f

#define BAR()    asm volatile("s_waitcnt lgkmcnt(0)\n\ts_barrier" ::: "memory")
#define WAITV(N) asm volatile("s_waitcnt vmcnt(" #N ")" ::: "memory")
#define WAITL()  asm volatile("s_waitcnt lgkmcnt(0)" ::: "memory")
#define CFENCE() asm volatile("" ::: "memory")

// quad_perm DPP lane-exchange (no LDS port): 0xB1 = xor1, 0x4E = xor2
#define DPPF(v, CTRL) __int_as_float(__builtin_amdgcn_update_dpp( \
    0, __float_as_int(v), CTRL, 0xF, 0xF, true))
// ds_swizzle BitMode xor: offset = (xor<<10) | 0x1F
#define SWZF(v, OFF)  __int_as_float(__builtin_amdgcn_ds_swizzle( \
    __float_as_int(v), OFF))

typedef const __attribute__((address_space(1))) void* gas1_t;
typedef __attribute__((address_space(3))) void*       las3_t;
typedef float v2f __attribute__((ext_vector_type(2)));

__global__ __launch_bounds__(256, 2)
void bsq_fused(const float* __restrict__ x,
               const float* __restrict__ Wp,
               const float* __restrict__ bp,
               const float* __restrict__ Wr,
               const float* __restrict__ br,
               float* __restrict__ out)
{
    const int tid = threadIdx.x;
    const int w   = tid >> 6;      // wave 0..3: c-quarter
    const int l   = tid & 63;
    const int cl  = l & 15;        // c-lane within wave
    const int dq  = l >> 4;        // d-quarter: lane's d = dq*4 + (0..3)
    const int cg  = l >> 4;        // fixup layout (unchanged from r12)
    const int dg  = l & 15;        // fixup layout

    __shared__ __align__(16) float  xl[4 * 1024];     // 16 KB ring: 4 slots x 2 rows
    __shared__ __align__(16) float  zp[TILE][16][4];  // 4 KB: [row][d][wave]
    __shared__ __align__(16) double zb64[4][16];      // fixup exchange

    // ---- phase-A weights: wp2[d][j] covers lane's 8 c x 4 d ----
    // c(j<2)  = w*128 + cl*4 + 2j + {0,1}
    // c(j>=2) = w*128 + 64 + cl*4 + 2(j-2) + {0,1}
    const int ca = w * 128 + cl * 4;
    const int db = dq * 4;
    v2f wp2[4][4];
#pragma unroll
    for (int d = 0; d < 4; ++d) {
#pragma unroll
        for (int jj = 0; jj < 2; ++jj) {
            const float* pa = Wp + (ca + 2 * jj) * 16 + db + d;
            wp2[d][jj]     = (v2f){ pa[0], pa[16] };
            const float* pb = Wp + (ca + 64 + 2 * jj) * 16 + db + d;
            wp2[d][2 + jj] = (v2f){ pb[0], pb[16] };
        }
    }
    const float bpr = bp[db + (l & 3)];   // bias for recon lane-d
    const double bpd = (double)bp[dg];    // bias for fixup lane-d

    const int row0 = blockIdx.x * TILE;
    const float* xsrc = x + (size_t)row0 * 512 + (size_t)(l >> 5) * 512
                          + w * 128 + (l & 31) * 4;

    auto stage = [&](int s) {      // rows 2s,2s+1: wave's 1 KB region, 1 DMA
        __builtin_amdgcn_global_load_lds(
            (gas1_t)(xsrc + (size_t)(2 * s) * 512),
            (las3_t)(&xl[(s & 3) * 1024 + w * 256]), 16, 0, 0);
    };

    auto dot_part = [&](int s, int p, v2f (&acc)[4]) {
        const float* bx = &xl[(s & 3) * 1024 + w * 256 + p * 128];
        const float4 xr0 = *(const float4*)(bx + cl * 4);        // c ca..ca+3
        const float4 xr1 = *(const float4*)(bx + 64 + cl * 4);   // c ca+64..+67
        const v2f x0 = { xr0.x, xr0.y }, x1 = { xr0.z, xr0.w };
        const v2f x2 = { xr1.x, xr1.y }, x3 = { xr1.z, xr1.w };
#pragma unroll
        for (int d = 0; d < 4; ++d) {
            v2f a = x0 * wp2[d][0];
            a += x1 * wp2[d][1];
            a += x2 * wp2[d][2];
            a += x3 * wp2[d][3];
            acc[d] = a;
        }
    };

    auto fin_part = [&](int r, v2f (&acc)[4]) {
        const float v0 = acc[0].x + acc[0].y, v1 = acc[1].x + acc[1].y;
        const float v2 = acc[2].x + acc[2].y, v3 = acc[3].x + acc[3].y;
        // reduce-scatter over cl: xor1, xor2 (DPP), then xor4, xor8 (swizzle)
        const bool b0 = (l & 1), b1 = (l & 2);
        const float g01 = b0 ? v0 : v1;           // give what partner keeps
        const float k01 = (b0 ? v1 : v0) + DPPF(g01, 0xB1);  // d bit0 = l&1
        const float g23 = b0 ? v2 : v3;
        const float k23 = (b0 ? v3 : v2) + DPPF(g23, 0xB1);
        const float g2  = b1 ? k01 : k23;
        float z1 = (b1 ? k23 : k01) + DPPF(g2, 0x4E);        // d = l&3
        z1 += SWZF(z1, 0x101F);                   // xor4
        z1 += SWZF(z1, 0x201F);                   // xor8: summed over all cl
        if ((l & 12) == 0) zp[r][db + (l & 3)][w] = z1;
    };

    // ========== Phase A first half: rows 0..7 (pure dots) ==========
#pragma unroll
    for (int s = 0; s < 4; ++s) stage(s);
    WAITV(0);   // weights + slots 0..3 all resident; counting now exact

#pragma unroll 1
    for (int c = 0; c < 4; ++c) {
        v2f a0[4], a1[4];
        dot_part(c, 0, a0);            // slot pre-drained, no wait
        dot_part(c, 1, a1);
        CFENCE();
        WAITL();                       // slot's ds_reads retired -> reusable
        stage(c + 4);                  // rows 8..15 back into slots 0..3
        CFENCE();
        fin_part(2 * c, a0);
        fin_part(2 * c + 1, a1);
    }
    BAR();                             // zp rows 0..7 visible (lgkm-only)

    // ---- phase-B weights (v2f float2 slices) ----
    v2f wrv[16];
    const float2* Wr2 = (const float2*)Wr;
#pragma unroll
    for (int d = 0; d < 16; ++d) {
        const float2 t = Wr2[d * 256 + tid];
        wrv[d] = (v2f){ t.x, t.y };
    }
    const float2 brt = ((const float2*)br)[tid];
    const v2f br2v = (v2f){ brt.x, brt.y };
    WAITV(0);   // drains stages 4..7 + wr loads -> second half waits-free

    uint32_t amb = 0;                  // block-uniform ambiguity mask
    auto recon_row = [&](int r) {
        const int dl = db + (l & 3);   // this lane's d after reduce-scatter
        const float4 q = *(const float4*)&zp[r][dl][0];
        const float  z = (q.x + q.y) + (q.z + q.w) + bpr;
        if (__ballot(fabsf(z) < TAU)) amb |= (1u << r);
        // ballot bit for d sits at lane (d>>2)*16 + (d&3); rebuild natural m
        const unsigned long long bb = __ballot(z >= 0.0f);
        const int m = (int)((bb & 0xFull) | ((bb >> 12) & 0xF0ull)
                          | ((bb >> 24) & 0xF00ull) | ((bb >> 36) & 0xF000ull));
        v2f o = br2v;
#pragma unroll
        for (int d = 0; d < 16; ++d) {
            const float s = ((m >> d) & 1) ? 1.0f : -1.0f;
            o += (v2f){ s, s } * wrv[d];                  // v_pk_fma_f32
        }
        ((float2*)out)[(size_t)(row0 + r) * 256 + tid] = make_float2(o.x, o.y);
    };

    // == Phase A second half (rows 8..15) interleaved with recon rows 0..7 ==
#pragma unroll 1
    for (int c = 4; c < 8; ++c) {
        v2f a0[4], a1[4];
        dot_part(c, 0, a0);            // slots pre-drained by WAITV(0)
        dot_part(c, 1, a1);
        fin_part(2 * c, a0);
        fin_part(2 * c + 1, a1);
        recon_row(2 * (c - 4));
        recon_row(2 * (c - 4) + 1);
    }
    BAR();                             // zp rows 8..15 visible

    // ============ Phase B tail: recon rows 8..15 ============
#pragma unroll 2
    for (int r = 8; r < TILE; ++r) recon_row(r);

    // ===== Fixup: rare exact-f64 redo; uniform loop, matched barriers =====
    // (r12 layout: lane (cg=l>>4, dg=l&15), self-contained, proven)
#pragma unroll 1
    while (amb) {
        const int rr = __ffs(amb) - 1;
        amb &= amb - 1;
        const int row = row0 + rr;

        const float* xp = x + (size_t)row * 512 + w * 128 + cg * 4;
        double ad = 0.0;
#pragma unroll
        for (int j = 0; j < 8; ++j) {
            const float4 xf = *(const float4*)(xp + j * 16);
#pragma unroll
            for (int e = 0; e < 4; ++e) {
                const float wpe = Wp[(w * 128 + j * 16 + cg * 4 + e) * 16 + dg];
                const float xe  = e == 0 ? xf.x : e == 1 ? xf.y
                               : e == 2 ? xf.z : xf.w;
                ad = fma((double)xe, (double)wpe, ad);
            }
        }
        ad += __shfl_xor(ad, 16, 64);
        ad += __shfl_xor(ad, 32, 64);
        if (l < 16) zb64[w][l] = ad;
        BAR();
        const double zd = (zb64[0][dg] + zb64[1][dg])
                        + (zb64[2][dg] + zb64[3][dg]) + bpd;
        const int m = (int)(__ballot(zd >= 0.0) & 0xFFFFull);
        BAR();   // zb64 reads retired before next fixup row's rewrite

        v2f o = br2v;
#pragma unroll
        for (int d = 0; d < 16; ++d) {
            const float s = ((m >> d) & 1) ? 1.0f : -1.0f;
            o += (v2f){ s, s } * wrv[d];
        }
        ((float2*)out)[(size_t)row * 256 + tid] = make_float2(o.x, o.y);
    }
}

extern "C" void kernel_launch(void* const* d_in, const int* in_sizes, int n_in,
                              void* d_out, int out_size, void* d_ws, size_t ws_size,
                              hipStream_t stream) {
    const float* x  = (const float*)d_in[0];
    const float* Wp = (const float*)d_in[1];
    const float* bp = (const float*)d_in[2];
    const float* Wr = (const float*)d_in[3];
    const float* br = (const float*)d_in[4];
    float* out = (float*)d_out;

    bsq_fused<<<BLOCKS, 256, 0, stream>>>(x, Wp, bp, Wr, br, out);
}

// Round 15
// 63.114 us; speedup vs baseline: 1.2214x; 1.0696x over previous
//
#include <hip/hip_runtime.h>
#include <stdint.h>

// Fused BSQ: recon = sign(x @ Wp + bp) @ Wr + br   (L2-normalize is sign-invariant)
// x: [65536][512] f32, Wp: [512][16], bp: [16], Wr: [16][512], br: [512]
//
// Round-15 = round-12 (best: 63.8us) + ONE change: nontemporal output stores.
// Theory: per timed replay, 133 MB of output streaming through L2/L3 evicts
// half of x from the 256 MB Infinity Cache (FETCH_SIZE = 67 MB = x/2 proves
// partial residency). nt stores (no cache allocate) leave L3 to x -> reads
// become L3-hits, HBM channel goes write-only (~42us floor at ~3.15 TB/s).
// Everything else identical to r12:
//  - 4-slot x 2-row global_load_lds ring, two WAITV(0)/block (counting immune
//    to compiler-sunk loads), no per-chunk vm-waits.
//  - pk-FMA dot (v2f), 2-shuffle cg-reduce, zp[row][d][wave] conflict-free.
//  - Recon rows 0..7 interleaved into dot-chunks of rows 8..15; float2 nt
//    stores; block-uniform ambiguity mask; rare (~2%) exact-f64 fixup with
//    matched barriers. Reference signs are f64-exact: rounds 1-14 absmax 0.0.

#define ROWS   65536
#define TILE   16
#define BLOCKS (ROWS / TILE)   // 4096
#define TAU    1e-3f

#define BAR()    asm volatile("s_waitcnt lgkmcnt(0)\n\ts_barrier" ::: "memory")
#define WAITV(N) asm volatile("s_waitcnt vmcnt(" #N ")" ::: "memory")
#define WAITL()  asm volatile("s_waitcnt lgkmcnt(0)" ::: "memory")
#define CFENCE() asm volatile("" ::: "memory")

typedef const __attribute__((address_space(1))) void* gas1_t;
typedef __attribute__((address_space(3))) void*       las3_t;
typedef float v2f __attribute__((ext_vector_type(2)));

__global__ __launch_bounds__(256, 2)
void bsq_fused(const float* __restrict__ x,
               const float* __restrict__ Wp,
               const float* __restrict__ bp,
               const float* __restrict__ Wr,
               const float* __restrict__ br,
               float* __restrict__ out)
{
    const int tid = threadIdx.x;
    const int w   = tid >> 6;      // wave 0..3: c-quarter
    const int l   = tid & 63;
    const int cg  = l >> 4;        // 0..3
    const int dg  = l & 15;        // 0..15: this lane's d

    __shared__ __align__(16) float  xl[4 * 1024];     // 16 KB ring: 4 slots x 2 rows
    __shared__ __align__(16) float  zp[TILE][16][4];  // 4 KB: [row][d][wave]
    __shared__ __align__(16) double zb64[4][16];      // fixup exchange

    // ---- phase-A weights as v2f pairs (issued before the stages) ----
    v2f wpA[8], wpB[8];
#pragma unroll
    for (int j = 0; j < 8; ++j) {
        const float* wj = Wp + (w * 128 + j * 16 + cg * 4) * 16 + dg;
        wpA[j] = (v2f){ wj[0],  wj[16] };
        wpB[j] = (v2f){ wj[32], wj[48] };
    }
    const float bpf = bp[dg];

    const int row0 = blockIdx.x * TILE;
    const float* xsrc = x + (size_t)row0 * 512 + (size_t)(l >> 5) * 512
                          + w * 128 + (l & 31) * 4;

    auto stage = [&](int s) {      // rows 2s,2s+1: wave's 1 KB region, 1 DMA
        __builtin_amdgcn_global_load_lds(
            (gas1_t)(xsrc + (size_t)(2 * s) * 512),
            (las3_t)(&xl[(s & 3) * 1024 + w * 256]), 16, 0, 0);
    };

    auto dot_part = [&](int s, int p, v2f& accA, v2f& accB) {
        const float* bx = &xl[(s & 3) * 1024 + w * 256 + p * 128 + cg * 4];
        float4 xr[8];
#pragma unroll
        for (int j = 0; j < 8; ++j) xr[j] = *(const float4*)(bx + j * 16);
        accA = (v2f){0.f, 0.f};  accB = (v2f){0.f, 0.f};
#pragma unroll
        for (int j = 0; j < 8; ++j) {
            accA += (v2f){ xr[j].x, xr[j].y } * wpA[j];   // v_pk_fma_f32
            accB += (v2f){ xr[j].z, xr[j].w } * wpB[j];
        }
    };
    auto fin_part = [&](int r, v2f accA, v2f accB) {
        float a = (accA.x + accA.y) + (accB.x + accB.y);
        a += __shfl_xor(a, 16, 64);    // reduce over cg (lane bits 4,5)
        a += __shfl_xor(a, 32, 64);
        if (l < 16) zp[r][l][w] = a;   // 2-way bank alias = free
    };

    // ========== Phase A first half: rows 0..7 (pure dots) ==========
#pragma unroll
    for (int s = 0; s < 4; ++s) stage(s);
    WAITV(0);   // weights + slots 0..3 all resident; counting now exact

#pragma unroll 1
    for (int c = 0; c < 4; ++c) {
        v2f aA0, aB0, aA1, aB1;
        dot_part(c, 0, aA0, aB0);      // slot pre-drained, no wait
        dot_part(c, 1, aA1, aB1);
        CFENCE();
        WAITL();                       // slot's ds_reads retired -> reusable
        stage(c + 4);                  // rows 8..15 back into slots 0..3
        CFENCE();
        fin_part(2 * c, aA0, aB0);
        fin_part(2 * c + 1, aA1, aB1);
    }
    BAR();                             // zp rows 0..7 visible (lgkm-only)

    // ---- phase-B weights (v2f float2 slices; VGPR stays ~64) ----
    v2f wrv[16];
    const float2* Wr2 = (const float2*)Wr;
#pragma unroll
    for (int d = 0; d < 16; ++d) {
        const float2 t = Wr2[d * 256 + tid];
        wrv[d] = (v2f){ t.x, t.y };
    }
    const float2 brt = ((const float2*)br)[tid];
    const v2f br2v = (v2f){ brt.x, brt.y };
    WAITV(0);   // drains stages 4..7 + wr loads -> second half waits-free

    uint32_t amb = 0;                  // block-uniform ambiguity mask
    auto recon_row = [&](int r) {
        const float4 q = *(const float4*)&zp[r][dg][0];   // 1 b128, conflict-free
        const float  z = (q.x + q.y) + (q.z + q.w) + bpf;
        if (__ballot(fabsf(z) < TAU)) amb |= (1u << r);
        const int m = (int)(__ballot(z >= 0.0f) & 0xFFFFull);
        v2f o = br2v;
#pragma unroll
        for (int d = 0; d < 16; ++d) {
            const float s = ((m >> d) & 1) ? 1.0f : -1.0f;
            o += (v2f){ s, s } * wrv[d];                  // v_pk_fma_f32
        }
        __builtin_nontemporal_store(
            o, (v2f*)((float2*)out + (size_t)(row0 + r) * 256 + tid));
    };

    // == Phase A second half (rows 8..15) interleaved with recon rows 0..7 ==
#pragma unroll 1
    for (int c = 4; c < 8; ++c) {
        v2f aA0, aB0, aA1, aB1;
        dot_part(c, 0, aA0, aB0);      // slots pre-drained by WAITV(0)
        dot_part(c, 1, aA1, aB1);
        fin_part(2 * c, aA0, aB0);
        fin_part(2 * c + 1, aA1, aB1);
        recon_row(2 * (c - 4));
        recon_row(2 * (c - 4) + 1);
    }
    BAR();                             // zp rows 8..15 visible

    // ============ Phase B tail: recon rows 8..15 ============
#pragma unroll 2
    for (int r = 8; r < TILE; ++r) recon_row(r);

    // ===== Fixup: rare exact-f64 redo; uniform loop, matched barriers =====
    const double bpd = (double)bpf;
#pragma unroll 1
    while (amb) {
        const int rr = __ffs(amb) - 1;
        amb &= amb - 1;
        const int row = row0 + rr;

        const float* xp = x + (size_t)row * 512 + w * 128 + cg * 4;
        double ad = 0.0;
#pragma unroll
        for (int j = 0; j < 8; ++j) {
            const float4 xf = *(const float4*)(xp + j * 16);
#pragma unroll
            for (int e = 0; e < 4; ++e) {
                const float wpe = Wp[(w * 128 + j * 16 + cg * 4 + e) * 16 + dg];
                const float xe  = e == 0 ? xf.x : e == 1 ? xf.y
                               : e == 2 ? xf.z : xf.w;
                ad = fma((double)xe, (double)wpe, ad);
            }
        }
        ad += __shfl_xor(ad, 16, 64);
        ad += __shfl_xor(ad, 32, 64);
        if (l < 16) zb64[w][l] = ad;
        BAR();
        const double zd = (zb64[0][dg] + zb64[1][dg])
                        + (zb64[2][dg] + zb64[3][dg]) + bpd;
        const int m = (int)(__ballot(zd >= 0.0) & 0xFFFFull);
        BAR();   // zb64 reads retired before next fixup row's rewrite

        v2f o = br2v;
#pragma unroll
        for (int d = 0; d < 16; ++d) {
            const float s = ((m >> d) & 1) ? 1.0f : -1.0f;
            o += (v2f){ s, s } * wrv[d];
        }
        __builtin_nontemporal_store(
            o, (v2f*)((float2*)out + (size_t)row * 256 + tid));
    }
}

extern "C" void kernel_launch(void* const* d_in, const int* in_sizes, int n_in,
                              void* d_out, int out_size, void* d_ws, size_t ws_size,
                              hipStream_t stream) {
    const float* x  = (const float*)d_in[0];
    const float* Wp = (const float*)d_in[1];
    const float* bp = (const float*)d_in[2];
    const float* Wr = (const float*)d_in[3];
    const float* br = (const float*)d_in[4];
    float* out = (float*)d_out;

    bsq_fused<<<BLOCKS, 256, 0, stream>>>(x, Wp, bp, Wr, br, out);
}

// Round 16
// 62.265 us; speedup vs baseline: 1.2381x; 1.0136x over previous
//
#include <hip/hip_runtime.h>
#include <stdint.h>

// Fused BSQ: recon = sign(x @ Wp + bp) @ Wr + br   (L2-normalize is sign-invariant)
// x: [65536][512] f32, Wp: [512][16], bp: [16], Wr: [16][512], br: [512]
//
// Round-16 = round-15 minus the mid-block vmcnt(0) drain:
//  - ALL weights (wp, wr, br, bp) load up front; wr loads sit OLDEST in the
//    vm queue, so every later counted wait subsumes them (in-order retire).
//  - Second half uses counted WAITV(3+k) (k=0..3): newer-than-stage(4+k) =
//    (3-k) stages + 2k recon stores. No full drain anywhere mid-block; the
//    only WAITV(0) is the one-time post-prologue drain.
//  - Everything else identical to r15: 4-slot x 2-row global_load_lds ring,
//    pk-FMA dot (v2f), 2-shuffle cg-reduce, zp[row][d][wave] conflict-free,
//    recon rows 0..7 interleaved into dot-chunks of rows 8..15, nt float2
//    stores, block-uniform ambiguity mask, rare (~2%) exact-f64 fixup with
//    matched barriers. Reference signs are f64-exact: rounds 1-15 absmax 0.0.

#define ROWS   65536
#define TILE   16
#define BLOCKS (ROWS / TILE)   // 4096
#define TAU    1e-3f

#define BAR()    asm volatile("s_waitcnt lgkmcnt(0)\n\ts_barrier" ::: "memory")
#define WAITV(N) asm volatile("s_waitcnt vmcnt(" #N ")" ::: "memory")
#define WAITL()  asm volatile("s_waitcnt lgkmcnt(0)" ::: "memory")
#define CFENCE() asm volatile("" ::: "memory")

typedef const __attribute__((address_space(1))) void* gas1_t;
typedef __attribute__((address_space(3))) void*       las3_t;
typedef float v2f __attribute__((ext_vector_type(2)));

__global__ __launch_bounds__(256, 2)
void bsq_fused(const float* __restrict__ x,
               const float* __restrict__ Wp,
               const float* __restrict__ bp,
               const float* __restrict__ Wr,
               const float* __restrict__ br,
               float* __restrict__ out)
{
    const int tid = threadIdx.x;
    const int w   = tid >> 6;      // wave 0..3: c-quarter
    const int l   = tid & 63;
    const int cg  = l >> 4;        // 0..3
    const int dg  = l & 15;        // 0..15: this lane's d

    __shared__ __align__(16) float  xl[4 * 1024];     // 16 KB ring: 4 slots x 2 rows
    __shared__ __align__(16) float  zp[TILE][16][4];  // 4 KB: [row][d][wave]
    __shared__ __align__(16) double zb64[4][16];      // fixup exchange

    // ---- phase-A weights as v2f pairs (issued before the stages) ----
    v2f wpA[8], wpB[8];
#pragma unroll
    for (int j = 0; j < 8; ++j) {
        const float* wj = Wp + (w * 128 + j * 16 + cg * 4) * 16 + dg;
        wpA[j] = (v2f){ wj[0],  wj[16] };
        wpB[j] = (v2f){ wj[32], wj[48] };
    }
    const float bpf = bp[dg];

    const int row0 = blockIdx.x * TILE;
    const float* xsrc = x + (size_t)row0 * 512 + (size_t)(l >> 5) * 512
                          + w * 128 + (l & 31) * 4;

    auto stage = [&](int s) {      // rows 2s,2s+1: wave's 1 KB region, 1 DMA
        __builtin_amdgcn_global_load_lds(
            (gas1_t)(xsrc + (size_t)(2 * s) * 512),
            (las3_t)(&xl[(s & 3) * 1024 + w * 256]), 16, 0, 0);
    };

    auto dot_part = [&](int s, int p, v2f& accA, v2f& accB) {
        const float* bx = &xl[(s & 3) * 1024 + w * 256 + p * 128 + cg * 4];
        float4 xr[8];
#pragma unroll
        for (int j = 0; j < 8; ++j) xr[j] = *(const float4*)(bx + j * 16);
        accA = (v2f){0.f, 0.f};  accB = (v2f){0.f, 0.f};
#pragma unroll
        for (int j = 0; j < 8; ++j) {
            accA += (v2f){ xr[j].x, xr[j].y } * wpA[j];   // v_pk_fma_f32
            accB += (v2f){ xr[j].z, xr[j].w } * wpB[j];
        }
    };
    auto fin_part = [&](int r, v2f accA, v2f accB) {
        float a = (accA.x + accA.y) + (accB.x + accB.y);
        a += __shfl_xor(a, 16, 64);    // reduce over cg (lane bits 4,5)
        a += __shfl_xor(a, 32, 64);
        if (l < 16) zp[r][l][w] = a;   // 2-way bank alias = free
    };

    // ================= prologue: stages + ONE full drain =================
#pragma unroll
    for (int s = 0; s < 4; ++s) stage(s);
    WAITV(0);   // wp/bp + slots 0..3 resident; vm-counting exact from here

    // ---- phase-B weights NOW (oldest vm ops; subsumed by any later wait) ----
    v2f wrv[16];
    const float2* Wr2 = (const float2*)Wr;
#pragma unroll
    for (int d = 0; d < 16; ++d) {
        const float2 t = Wr2[d * 256 + tid];
        wrv[d] = (v2f){ t.x, t.y };
    }
    const float2 brt = ((const float2*)br)[tid];
    const v2f br2v = (v2f){ brt.x, brt.y };
    CFENCE();

    // ========== Phase A first half: rows 0..7 (pure dots) ==========
#pragma unroll 1
    for (int c = 0; c < 4; ++c) {
        v2f aA0, aB0, aA1, aB1;
        dot_part(c, 0, aA0, aB0);      // slot pre-drained, no wait
        dot_part(c, 1, aA1, aB1);
        CFENCE();
        WAITL();                       // slot's ds_reads retired -> reusable
        stage(c + 4);                  // rows 8..15 back into slots 0..3
        CFENCE();
        fin_part(2 * c, aA0, aB0);
        fin_part(2 * c + 1, aA1, aB1);
    }
    BAR();                             // zp rows 0..7 visible (lgkm-only)

    uint32_t amb = 0;                  // block-uniform ambiguity mask
    auto recon_row = [&](int r) {
        const float4 q = *(const float4*)&zp[r][dg][0];   // 1 b128, conflict-free
        const float  z = (q.x + q.y) + (q.z + q.w) + bpf;
        if (__ballot(fabsf(z) < TAU)) amb |= (1u << r);
        const int m = (int)(__ballot(z >= 0.0f) & 0xFFFFull);
        v2f o = br2v;
#pragma unroll
        for (int d = 0; d < 16; ++d) {
            const float s = ((m >> d) & 1) ? 1.0f : -1.0f;
            o += (v2f){ s, s } * wrv[d];                  // v_pk_fma_f32
        }
        __builtin_nontemporal_store(
            o, (v2f*)((float2*)out + (size_t)(row0 + r) * 256 + tid));
    };

    // == Phase A second half (rows 8..15) interleaved with recon rows 0..7 ==
    // Counted waits: before chunk 4+k's dots, newer-than-stage(4+k) =
    // (3-k) stages + 2k stores -> WAITV(3+k). wr loads are older -> covered.
    {
        v2f aA0, aB0, aA1, aB1;
        WAITV(3);
        dot_part(4, 0, aA0, aB0); dot_part(4, 1, aA1, aB1);
        fin_part(8, aA0, aB0); fin_part(9, aA1, aB1);
        recon_row(0); recon_row(1);
        WAITV(4);
        dot_part(5, 0, aA0, aB0); dot_part(5, 1, aA1, aB1);
        fin_part(10, aA0, aB0); fin_part(11, aA1, aB1);
        recon_row(2); recon_row(3);
        WAITV(5);
        dot_part(6, 0, aA0, aB0); dot_part(6, 1, aA1, aB1);
        fin_part(12, aA0, aB0); fin_part(13, aA1, aB1);
        recon_row(4); recon_row(5);
        WAITV(6);
        dot_part(7, 0, aA0, aB0); dot_part(7, 1, aA1, aB1);
        fin_part(14, aA0, aB0); fin_part(15, aA1, aB1);
        recon_row(6); recon_row(7);
    }
    BAR();                             // zp rows 8..15 visible

    // ============ Phase B tail: recon rows 8..15 ============
#pragma unroll 2
    for (int r = 8; r < TILE; ++r) recon_row(r);

    // ===== Fixup: rare exact-f64 redo; uniform loop, matched barriers =====
    const double bpd = (double)bpf;
#pragma unroll 1
    while (amb) {
        const int rr = __ffs(amb) - 1;
        amb &= amb - 1;
        const int row = row0 + rr;

        const float* xp = x + (size_t)row * 512 + w * 128 + cg * 4;
        double ad = 0.0;
#pragma unroll
        for (int j = 0; j < 8; ++j) {
            const float4 xf = *(const float4*)(xp + j * 16);
#pragma unroll
            for (int e = 0; e < 4; ++e) {
                const float wpe = Wp[(w * 128 + j * 16 + cg * 4 + e) * 16 + dg];
                const float xe  = e == 0 ? xf.x : e == 1 ? xf.y
                               : e == 2 ? xf.z : xf.w;
                ad = fma((double)xe, (double)wpe, ad);
            }
        }
        ad += __shfl_xor(ad, 16, 64);
        ad += __shfl_xor(ad, 32, 64);
        if (l < 16) zb64[w][l] = ad;
        BAR();
        const double zd = (zb64[0][dg] + zb64[1][dg])
                        + (zb64[2][dg] + zb64[3][dg]) + bpd;
        const int m = (int)(__ballot(zd >= 0.0) & 0xFFFFull);
        BAR();   // zb64 reads retired before next fixup row's rewrite

        v2f o = br2v;
#pragma unroll
        for (int d = 0; d < 16; ++d) {
            const float s = ((m >> d) & 1) ? 1.0f : -1.0f;
            o += (v2f){ s, s } * wrv[d];
        }
        __builtin_nontemporal_store(
            o, (v2f*)((float2*)out + (size_t)row * 256 + tid));
    }
}

extern "C" void kernel_launch(void* const* d_in, const int* in_sizes, int n_in,
                              void* d_out, int out_size, void* d_ws, size_t ws_size,
                              hipStream_t stream) {
    const float* x  = (const float*)d_in[0];
    const float* Wp = (const float*)d_in[1];
    const float* bp = (const float*)d_in[2];
    const float* Wr = (const float*)d_in[3];
    const float* br = (const float*)d_in[4];
    float* out = (float*)d_out;

    bsq_fused<<<BLOCKS, 256, 0, stream>>>(x, Wp, bp, Wr, br, out);
}